// Round 1
// baseline (79.126 us; speedup 1.0000x reference)
//
#include <hip/hip_runtime.h>
#include <hip/hip_bf16.h>
#include <stdint.h>

// GraphRec attention aggregator, fused single kernel.
// B=16384 nodes, D=50 neighbors, E=64 embed. One wave per node b.
// Layers computed transposed via MFMA: H1^T = W1^T @ X^T, H2^T = W2^T @ H1^T.

#define BATCH 16384
#define DEG 50

typedef __attribute__((ext_vector_type(8))) short short8;   // 8 bf16 = 4 VGPR
typedef __attribute__((ext_vector_type(4))) float f32x4;

__device__ __forceinline__ unsigned short f2bf(float f) {
    union { float f; unsigned u; } v; v.f = f;
    return (unsigned short)((v.u + 0x7FFFu + ((v.u >> 16) & 1u)) >> 16); // RNE
}

__global__ __launch_bounds__(256, 2)
void graphrec_fused(const int* __restrict__ nodes, const int* __restrict__ neighbors,
                    const float* __restrict__ u_to_e,
                    const float* __restrict__ w1, const float* __restrict__ b1,
                    const float* __restrict__ w2, const float* __restrict__ b2,
                    const float* __restrict__ w3,
                    float* __restrict__ out)
{
    // A-operand frags (W1^T: K=128 -> 4 kt x 4 t; W2^T: K=64 -> 2 kt x 4 t)
    __shared__ short8 lds_a1[16][64];
    __shared__ short8 lds_a2[8][64];
    __shared__ int    lds_nbr[4][64];
    __shared__ unsigned short lds_h1[4][1024];  // per-wave 16x64 bf16, XOR-swizzled

    const int tid  = threadIdx.x;
    const int lane = tid & 63;
    const int wid  = tid >> 6;
    const int q    = lane >> 4;   // k-group
    const int r    = lane & 15;   // row/col within tile

    // ---- pack weight fragments into LDS (once per block) ----
    // A layout (16x16x32): lane l holds A[l&15][8*(l>>4)+j], j=0..7
    for (int f = wid; f < 16; f += 4) {
        const int kt = f >> 2, t = f & 3;
        short8 s;
        #pragma unroll
        for (int j = 0; j < 8; ++j)
            s[j] = (short)f2bf(w1[(32*kt + 8*q + j)*64 + 16*t + r]);
        lds_a1[f][lane] = s;
    }
    for (int f = wid; f < 8; f += 4) {
        const int kt2 = f >> 2, t2 = f & 3;
        short8 s;
        #pragma unroll
        for (int j = 0; j < 8; ++j)
            s[j] = (short)f2bf(w2[(32*kt2 + 8*q + j)*64 + 16*t2 + r]);
        lds_a2[f][lane] = s;
    }

    const int b    = blockIdx.x * 4 + wid;
    const int node = nodes[b];
    lds_nbr[wid][lane] = (lane < DEG) ? neighbors[b * DEG + lane] : 0;
    __syncthreads();

    // per-lane bias/weight constants: index n = 16*t + 4*q + reg
    f32x4 b1v[4], b2v[4], w3v[4];
    #pragma unroll
    for (int t = 0; t < 4; ++t) {
        b1v[t] = *reinterpret_cast<const f32x4*>(b1 + 16*t + 4*q);
        b2v[t] = *reinterpret_cast<const f32x4*>(b2 + 16*t + 4*q);
        w3v[t] = *reinterpret_cast<const f32x4*>(w3 + 16*t + 4*q);
    }

    // ---- gather X B-frags: X^T[k][m], col m = 16*mt + r, k = 32*kt + 8*q + j ----
    short8 xf[4][2];   // E_n part (k < 64)
    #pragma unroll
    for (int mt = 0; mt < 4; ++mt) {
        const int nb = lds_nbr[wid][16*mt + r];
        const float* base = u_to_e + (size_t)nb * 64;
        #pragma unroll
        for (int kt = 0; kt < 2; ++kt) {
            f32x4 a = *reinterpret_cast<const f32x4*>(base + 32*kt + 8*q);
            f32x4 c = *reinterpret_cast<const f32x4*>(base + 32*kt + 8*q + 4);
            short8 s;
            s[0]=(short)f2bf(a[0]); s[1]=(short)f2bf(a[1]);
            s[2]=(short)f2bf(a[2]); s[3]=(short)f2bf(a[3]);
            s[4]=(short)f2bf(c[0]); s[5]=(short)f2bf(c[1]);
            s[6]=(short)f2bf(c[2]); s[7]=(short)f2bf(c[3]);
            xf[mt][kt] = s;
        }
    }
    short8 xu[2];      // e_u broadcast part (k >= 64), same for all m
    {
        const float* base = u_to_e + (size_t)node * 64;
        #pragma unroll
        for (int kt = 0; kt < 2; ++kt) {
            f32x4 a = *reinterpret_cast<const f32x4*>(base + 32*kt + 8*q);
            f32x4 c = *reinterpret_cast<const f32x4*>(base + 32*kt + 8*q + 4);
            short8 s;
            s[0]=(short)f2bf(a[0]); s[1]=(short)f2bf(a[1]);
            s[2]=(short)f2bf(a[2]); s[3]=(short)f2bf(a[3]);
            s[4]=(short)f2bf(c[0]); s[5]=(short)f2bf(c[1]);
            s[6]=(short)f2bf(c[2]); s[7]=(short)f2bf(c[3]);
            xu[kt] = s;
        }
    }

    // ---- layer 1: acc1[t][mt] = (W1^T @ X^T) tile; D: row n1=16t+4q+reg, col m=16mt+r ----
    f32x4 acc1[4][4];
    #pragma unroll
    for (int t = 0; t < 4; ++t)
        #pragma unroll
        for (int mt = 0; mt < 4; ++mt)
            acc1[t][mt] = (f32x4){0.f, 0.f, 0.f, 0.f};
    #pragma unroll
    for (int kt = 0; kt < 4; ++kt) {
        #pragma unroll
        for (int t = 0; t < 4; ++t) {
            short8 a = lds_a1[kt*4 + t][lane];
            #pragma unroll
            for (int mt = 0; mt < 4; ++mt) {
                short8 bb = (kt < 2) ? xf[mt][kt] : xu[kt - 2];
                acc1[t][mt] = __builtin_amdgcn_mfma_f32_16x16x32_bf16(a, bb, acc1[t][mt], 0, 0, 0);
            }
        }
    }

    // ---- per m-tile: bias+relu -> LDS (swizzled) -> layer-2 B-frags -> scores ----
    unsigned short* h1base = lds_h1[wid];
    float sc[4];
    #pragma unroll
    for (int mt = 0; mt < 4; ++mt) {
        #pragma unroll
        for (int t = 0; t < 4; ++t) {
            float h0 = fmaxf(acc1[t][mt][0] + b1v[t][0], 0.f);
            float h1 = fmaxf(acc1[t][mt][1] + b1v[t][1], 0.f);
            float h2 = fmaxf(acc1[t][mt][2] + b1v[t][2], 0.f);
            float h3 = fmaxf(acc1[t][mt][3] + b1v[t][3], 0.f);
            unsigned lo = (unsigned)f2bf(h0) | ((unsigned)f2bf(h1) << 16);
            unsigned hi = (unsigned)f2bf(h2) | ((unsigned)f2bf(h3) << 16);
            // H1 block layout [m_local=r][n1], row = 128 B, byte-XOR swizzle vs bank conflicts
            int off = r * 128 + (((16*t + 4*q) * 2) ^ ((r & 7) << 4));
            *reinterpret_cast<uint2*>((char*)h1base + off) = make_uint2(lo, hi);
        }
        // B2 frag: col m = 16mt+r, k = n1 = 32*kt2 + 8q + j  (same-wave LDS RAW, in-order)
        f32x4 acc2[4];
        #pragma unroll
        for (int t2 = 0; t2 < 4; ++t2) acc2[t2] = (f32x4){0.f, 0.f, 0.f, 0.f};
        #pragma unroll
        for (int kt2 = 0; kt2 < 2; ++kt2) {
            int roff = r * 128 + (((32*kt2 + 8*q) * 2) ^ ((r & 7) << 4));
            short8 b2f = *reinterpret_cast<const short8*>((const char*)h1base + roff);
            #pragma unroll
            for (int t2 = 0; t2 < 4; ++t2) {
                short8 a = lds_a2[kt2*4 + t2][lane];
                acc2[t2] = __builtin_amdgcn_mfma_f32_16x16x32_bf16(a, b2f, acc2[t2], 0, 0, 0);
            }
        }
        float sp = 0.f;
        #pragma unroll
        for (int t2 = 0; t2 < 4; ++t2) {
            #pragma unroll
            for (int reg = 0; reg < 4; ++reg)
                sp += fmaxf(acc2[t2][reg] + b2v[t2][reg], 0.f) * w3v[t2][reg];
        }
        sp += __shfl_xor(sp, 16, 64);
        sp += __shfl_xor(sp, 32, 64);
        sc[mt] = sp;   // score for m = 16*mt + r (replicated over q)
    }

    // ---- softmax over m < 50 (cross-lane over r) ----
    float mx = fmaxf(fmaxf(sc[0], sc[1]), sc[2]);
    if (r < 2) mx = fmaxf(mx, sc[3]);
    mx = fmaxf(mx, __shfl_xor(mx, 1, 64));
    mx = fmaxf(mx, __shfl_xor(mx, 2, 64));
    mx = fmaxf(mx, __shfl_xor(mx, 4, 64));
    mx = fmaxf(mx, __shfl_xor(mx, 8, 64));
    float e0 = __expf(sc[0] - mx);
    float e1 = __expf(sc[1] - mx);
    float e2 = __expf(sc[2] - mx);
    float e3 = (r < 2) ? __expf(sc[3] - mx) : 0.f;
    float sum = e0 + e1 + e2 + e3;
    sum += __shfl_xor(sum, 1, 64);
    sum += __shfl_xor(sum, 2, 64);
    sum += __shfl_xor(sum, 4, 64);
    sum += __shfl_xor(sum, 8, 64);
    float inv = 1.f / sum;
    float att[4] = { e0 * inv, e1 * inv, e2 * inv, e3 * inv };

    // ---- aggregation in fp32: out[b][c] = sum_d att[d] * e_n[d][c], c = lane ----
    float oacc = 0.f;
    #pragma unroll
    for (int mt = 0; mt < 4; ++mt) {
        const int mmax = (mt == 3) ? 2 : 16;
        #pragma unroll
        for (int rr = 0; rr < mmax; ++rr) {
            float a = __shfl(att[mt], rr, 64);         // att for m = 16*mt + rr
            int nb = lds_nbr[wid][16*mt + rr];          // broadcast LDS read
            oacc = fmaf(a, u_to_e[(size_t)nb * 64 + lane], oacc);
        }
    }
    out[(size_t)b * 64 + lane] = oacc;
}

extern "C" void kernel_launch(void* const* d_in, const int* in_sizes, int n_in,
                              void* d_out, int out_size, void* d_ws, size_t ws_size,
                              hipStream_t stream) {
    const int*   nodes     = (const int*)d_in[0];
    const int*   neighbors = (const int*)d_in[1];
    const float* u_to_e    = (const float*)d_in[2];
    const float* w1        = (const float*)d_in[3];
    const float* b1        = (const float*)d_in[4];
    const float* w2        = (const float*)d_in[5];
    const float* b2        = (const float*)d_in[6];
    const float* w3        = (const float*)d_in[7];
    // d_in[8] = b3: constant shift, exactly cancelled by softmax — omitted.
    graphrec_fused<<<dim3(BATCH / 4), dim3(256), 0, stream>>>(
        nodes, neighbors, u_to_e, w1, b1, w2, b2, w3, (float*)d_out);
}